// Round 1
// baseline (12863.092 us; speedup 1.0000x reference)
//
#include <hip/hip_runtime.h>
#include <math.h>

// Problem constants
#define NN 2048
#define MM 16
#define DD 512
#define DE 128
#define HH 8
#define GG 50
#define DH 64
#define DEH 16

__device__ __forceinline__ float gelu_f(float x) {
    return 0.5f * x * (1.0f + erff(x * 0.70710678118654752440f));
}

__device__ __forceinline__ float wsum(float v) {
#pragma unroll
    for (int o = 32; o; o >>= 1) v += __shfl_xor(v, o, 64);
    return v;
}

// ---------------------------------------------------------------------------
// Row-wise (optional GELU) + LayerNorm, in-place capable. grid = rows, 256 thr
// ---------------------------------------------------------------------------
__global__ __launch_bounds__(256) void act_ln_kernel(float* __restrict__ y,
                                                     const float* __restrict__ x,
                                                     int C, int do_gelu) {
    int row = blockIdx.x, tid = threadIdx.x;
    int nv = C >> 8;  // C is 512 or 2048
    float v[8];
    float s = 0.f, ss = 0.f;
    for (int i = 0; i < nv; ++i) {
        float val = x[(size_t)row * C + tid + (i << 8)];
        if (do_gelu) val = gelu_f(val);
        v[i] = val;
        s += val;
        ss += val * val;
    }
    __shared__ float red[4][2];
    s = wsum(s);
    ss = wsum(ss);
    int wid = tid >> 6, lane = tid & 63;
    if (lane == 0) { red[wid][0] = s; red[wid][1] = ss; }
    __syncthreads();
    s = red[0][0] + red[1][0] + red[2][0] + red[3][0];
    ss = red[0][1] + red[1][1] + red[2][1] + red[3][1];
    float mean = s / (float)C;
    float var = ss / (float)C - mean * mean;
    float rs = rsqrtf(var + 1e-5f);
    for (int i = 0; i < nv; ++i)
        y[(size_t)row * C + tid + (i << 8)] = (v[i] - mean) * rs;
}

// ---------------------------------------------------------------------------
// Generic fp32 GEMM: C = A[Mr,K] @ W[K,Nc] (+bias[Nc]) (+resid[Mr,Nc])
// 64x64 tile, 256 threads, 4x4 per thread, K-step 16.
// ---------------------------------------------------------------------------
__global__ __launch_bounds__(256) void gemm_kernel(const float* __restrict__ A,
                                                   const float* __restrict__ W,
                                                   const float* __restrict__ bias,
                                                   const float* __restrict__ resid,
                                                   float* __restrict__ C,
                                                   int Mr, int K, int Nc) {
    __shared__ float Ast[16][68];
    __shared__ float Ws[16][68];
    int tid = threadIdx.x;
    int tx = tid & 15, ty = tid >> 4;
    int row0 = blockIdx.y << 6, col0 = blockIdx.x << 6;
    int r0 = ty << 2, c0 = tx << 2;
    float acc[4][4] = {};
    for (int k0 = 0; k0 < K; k0 += 16) {
#pragma unroll
        for (int i = 0; i < 4; ++i) {
            int idx = tid + (i << 8);
            int r = idx >> 4, kk = idx & 15;
            int gr = row0 + r, gk = k0 + kk;
            Ast[kk][r] = (gr < Mr && gk < K) ? A[(size_t)gr * K + gk] : 0.f;
            int kw = idx >> 6, c = idx & 63;
            int gc = col0 + c, gkw = k0 + kw;
            Ws[kw][c] = (gkw < K && gc < Nc) ? W[(size_t)gkw * Nc + gc] : 0.f;
        }
        __syncthreads();
#pragma unroll
        for (int kk = 0; kk < 16; ++kk) {
            float4 a4 = *(const float4*)&Ast[kk][r0];
            float4 b4 = *(const float4*)&Ws[kk][c0];
            float av[4] = {a4.x, a4.y, a4.z, a4.w};
            float bv[4] = {b4.x, b4.y, b4.z, b4.w};
#pragma unroll
            for (int i = 0; i < 4; ++i)
#pragma unroll
                for (int j = 0; j < 4; ++j) acc[i][j] = fmaf(av[i], bv[j], acc[i][j]);
        }
        __syncthreads();
    }
#pragma unroll
    for (int i = 0; i < 4; ++i) {
        int r = row0 + r0 + i;
        if (r >= Mr) continue;
#pragma unroll
        for (int j = 0; j < 4; ++j) {
            int c = col0 + c0 + j;
            if (c >= Nc) continue;
            float v = acc[i][j];
            if (bias) v += bias[c];
            if (resid) v += resid[(size_t)r * Nc + c];
            C[(size_t)r * Nc + c] = v;
        }
    }
}

// ---------------------------------------------------------------------------
// Repack q,k heads from qkv [N,1536] into [N*H, 64] row-major
// ---------------------------------------------------------------------------
__global__ __launch_bounds__(256) void repack_qk(const float* __restrict__ qkv,
                                                 float* __restrict__ q2,
                                                 float* __restrict__ k2) {
    int idx = blockIdx.x * 256 + threadIdx.x;  // < 16384*64
    int r = idx >> 6, t = idx & 63;
    int n = r >> 3, h = r & 7;
    q2[idx] = qkv[(size_t)n * 1536 + h * 64 + t];
    k2[idx] = qkv[(size_t)n * 1536 + 512 + h * 64 + t];
}

// ---------------------------------------------------------------------------
// Frame-averaged edge features. One block per node n. 256 threads:
// 2 groups x 128 (group g handles m = m8*2+g). we2 staged in two 32KB halves.
// ---------------------------------------------------------------------------
__global__ __launch_bounds__(256) void edge_kernel(const float* __restrict__ coords,
                                                   const int* __restrict__ nbr,
                                                   const float* __restrict__ we1,
                                                   const float* __restrict__ be1,
                                                   const float* __restrict__ we2,
                                                   const float* __restrict__ be2,
                                                   float* __restrict__ edge) {
    __shared__ float we2h[64][128];
    __shared__ float projs[16][2];
    __shared__ float rns[16];
    __shared__ float hbuf[2][128];
    __shared__ float red[4][2];
    int n = blockIdx.x, tid = threadIdx.x;

    if (tid < 64) {
        int m = tid & 15;
        bool act = tid < 16;
        float cx = coords[n * 2], cy = coords[n * 2 + 1];
        int j = nbr[n * 16 + m];
        float rx = act ? (coords[j * 2] - cx) : 0.f;
        float ry = act ? (coords[j * 2 + 1] - cy) : 0.f;
        float rn = sqrtf(rx * rx + ry * ry);
        float mx = rx, my = ry;
#pragma unroll
        for (int o = 8; o; o >>= 1) { mx += __shfl_xor(mx, o, 16); my += __shfl_xor(my, o, 16); }
        mx *= 0.0625f;
        my *= 0.0625f;
        float xcx = act ? (rx - mx) : 0.f;
        float xcy = act ? (ry - my) : 0.f;
        float sxx = xcx * xcx, sxy = xcx * xcy, syy = xcy * xcy;
#pragma unroll
        for (int o = 8; o; o >>= 1) {
            sxx += __shfl_xor(sxx, o, 16);
            sxy += __shfl_xor(sxy, o, 16);
            syy += __shfl_xor(syy, o, 16);
        }
        // closed-form 2x2 symmetric eigendecomposition (ascending), f64 for robustness
        double a = (double)sxx, b = (double)sxy, c = (double)syy;
        double diff = 0.5 * (a - c);
        double disc = sqrt(diff * diff + b * b);
        double l2 = 0.5 * (a + c) + disc;
        double v2x = b, v2y = l2 - a;
        double nn2 = sqrt(v2x * v2x + v2y * v2y);
        if (nn2 < 1e-30) { v2x = (a >= c) ? 1.0 : 0.0; v2y = 1.0 - v2x; nn2 = 1.0; }
        v2x /= nn2;
        v2y /= nn2;
        double v1x = -v2y, v1y = v2x;  // eigenvector of smaller eigenvalue
        if (act) {
            projs[m][0] = (float)((double)xcx * v1x + (double)xcy * v1y);
            projs[m][1] = (float)((double)xcx * v2x + (double)xcy * v2y);
            rns[m] = rn;
        }
    }
    __syncthreads();

    int g = tid >> 7, l = tid & 127;
    int wid = tid >> 6, lane = tid & 63;
    float w10 = we1[l], w11 = we1[128 + l], w12 = we1[256 + l];
    float b1 = be1[l], b2 = be2[l];
    const float opsx[4] = {-1.f, -1.f, 1.f, 1.f};
    const float opsy[4] = {-1.f, 1.f, -1.f, 1.f};
    float accs[8] = {0.f, 0.f, 0.f, 0.f, 0.f, 0.f, 0.f, 0.f};

    for (int half = 0; half < 2; ++half) {
        __syncthreads();
        for (int i = tid; i < 64 * 128; i += 256) we2h[i >> 7][i & 127] = we2[half * 64 * 128 + i];
        __syncthreads();
#pragma unroll
        for (int m8 = 0; m8 < 8; ++m8) {
            int m = m8 * 2 + g;
            float px = projs[m][0], py = projs[m][1], rn = rns[m];
#pragma unroll
            for (int f = 0; f < 4; ++f) {
                float hv = gelu_f(fmaf(opsx[f] * px, w10, fmaf(opsy[f] * py, w11, fmaf(rn, w12, b1))));
                float s = wsum(hv), ss = wsum(hv * hv);
                if (lane == 0) { red[wid][0] = s; red[wid][1] = ss; }
                __syncthreads();
                float S = red[g * 2][0] + red[g * 2 + 1][0];
                float SS = red[g * 2][1] + red[g * 2 + 1][1];
                float mean = S * (1.f / 128.f);
                float var = SS * (1.f / 128.f) - mean * mean;
                hbuf[g][l] = (hv - mean) * rsqrtf(var + 1e-5f);
                __syncthreads();
                float a = accs[m8];
                for (int t = 0; t < 64; ++t) a = fmaf(hbuf[g][half * 64 + t], we2h[t][l], a);
                accs[m8] = a;
                __syncthreads();
            }
        }
    }
#pragma unroll
    for (int m8 = 0; m8 < 8; ++m8)
        edge[((size_t)n * 16 + m8 * 2 + g) * 128 + l] = 0.25f * accs[m8] + b2;
}

// ---------------------------------------------------------------------------
// Fused attention-MLP logits. Block per n; wave per (m,h) row.
// val[c] = qp[n,h,c] + kp[j,h,c] + gep[j,c]-gep[n,c] + ba1[c] + edge_h@wa1_e
// logit = LN(gelu(val)) . wa2 + ba2   (LN+dot via 3 wave reductions, no store)
// ---------------------------------------------------------------------------
__global__ __launch_bounds__(256) void logits_kernel(const float* __restrict__ qp,
                                                     const float* __restrict__ kp,
                                                     const float* __restrict__ gep,
                                                     const float* __restrict__ edge,
                                                     const int* __restrict__ nbr,
                                                     const float* __restrict__ wa1,
                                                     const float* __restrict__ ba1,
                                                     const float* __restrict__ wa2,
                                                     const float* __restrict__ ba2,
                                                     float* __restrict__ logits) {
    __shared__ float wes[16 * 512];
    __shared__ float wa2s[512], ba1s[512], gepn[512];
    __shared__ float edl[16 * 128];
    __shared__ int jn[16];
    int n = blockIdx.x, tid = threadIdx.x;
    for (int i = tid; i < 16 * 512; i += 256) wes[i] = wa1[128 * 512 + i];
    for (int i = tid; i < 512; i += 256) {
        wa2s[i] = wa2[i];
        ba1s[i] = ba1[i];
        gepn[i] = gep[(size_t)n * 512 + i];
    }
    for (int i = tid; i < 16 * 128; i += 256) edl[i] = edge[(size_t)n * 2048 + i];
    if (tid < 16) jn[tid] = nbr[n * 16 + tid];
    __syncthreads();
    int wid = tid >> 6, lane = tid & 63;
    float sw = 0.f;
#pragma unroll
    for (int i = 0; i < 8; ++i) sw += wa2s[lane + 64 * i];
    sw = wsum(sw);
    float ba2v = ba2[0];
    for (int r = wid; r < 128; r += 4) {
        int m = r >> 3, h = r & 7;
        int j = jn[m];
        const float* qrow = qp + ((size_t)n * 8 + h) * 512;
        const float* krow = kp + ((size_t)j * 8 + h) * 512;
        const float* grow = gep + (size_t)j * 512;
        const float* ew = edl + m * 128 + h * 16;
        float s = 0.f, ss = 0.f, sd = 0.f;
#pragma unroll
        for (int i = 0; i < 8; ++i) {
            int c = lane + 64 * i;
            float val = qrow[c] + krow[c] + (grow[c] - gepn[c]) + ba1s[c];
#pragma unroll
            for (int t = 0; t < 16; ++t) val = fmaf(ew[t], wes[t * 512 + c], val);
            float gv = gelu_f(val);
            s += gv;
            ss += gv * gv;
            sd = fmaf(gv, wa2s[c], sd);
        }
        s = wsum(s);
        ss = wsum(ss);
        sd = wsum(sd);
        if (lane == 0) {
            float mean = s * (1.f / 512.f);
            float var = ss * (1.f / 512.f) - mean * mean;
            logits[((size_t)n * 8 + h) * 16 + m] = (sd - mean * sw) * rsqrtf(var + 1e-5f) + ba2v;
        }
    }
}

// ---------------------------------------------------------------------------
// Softmax over M per (n,h) + context aggregation -> scec [N, 640] = [sc | ec]
// ---------------------------------------------------------------------------
__global__ __launch_bounds__(256) void smax_agg_kernel(const float* __restrict__ logits,
                                                       const float* __restrict__ qkv,
                                                       const float* __restrict__ edge,
                                                       const int* __restrict__ nbr,
                                                       float* __restrict__ scec) {
    __shared__ float attn[128];
    __shared__ int jn[16];
    int n = blockIdx.x, tid = threadIdx.x;
    if (tid < 16) jn[tid] = nbr[n * 16 + tid];
    if (tid < 128) {
        float lg = logits[(size_t)n * 128 + tid];
        float mx = lg;
#pragma unroll
        for (int o = 8; o; o >>= 1) mx = fmaxf(mx, __shfl_xor(mx, o, 16));
        float e = expf(lg - mx);
        float se = e;
#pragma unroll
        for (int o = 8; o; o >>= 1) se += __shfl_xor(se, o, 16);
        attn[tid] = e / se;
    }
    __syncthreads();
    for (int c = tid; c < 640; c += 256) {
        float acc = 0.f;
        if (c < 512) {
            int h = c >> 6, t = c & 63;
#pragma unroll
            for (int m = 0; m < 16; ++m)
                acc = fmaf(attn[h * 16 + m], qkv[(size_t)jn[m] * 1536 + 1024 + h * 64 + t], acc);
        } else {
            int d = c - 512, h = d >> 4, t = d & 15;
#pragma unroll
            for (int m = 0; m < 16; ++m)
                acc = fmaf(attn[h * 16 + m], edge[((size_t)n * 16 + m) * 128 + h * 16 + t], acc);
        }
        scec[(size_t)n * 640 + c] = acc;
    }
}

// ---------------------------------------------------------------------------
extern "C" void kernel_launch(void* const* d_in, const int* in_sizes, int n_in,
                              void* d_out, int out_size, void* d_ws, size_t ws_size,
                              hipStream_t stream) {
    const float* gene_exp = (const float*)d_in[0];
    const float* token_embs = (const float*)d_in[1];
    const float* coords = (const float*)d_in[2];
    const int* nbr = (const int*)d_in[3];
    const float* w_qkv = (const float*)d_in[4];
    const float* b_qkv = (const float*)d_in[5];
    const float* wa1 = (const float*)d_in[6];
    const float* ba1 = (const float*)d_in[7];
    const float* wa2 = (const float*)d_in[8];
    const float* ba2 = (const float*)d_in[9];
    const float* we1 = (const float*)d_in[10];
    const float* be1 = (const float*)d_in[11];
    const float* we2 = (const float*)d_in[12];
    const float* be2 = (const float*)d_in[13];
    const float* wo1 = (const float*)d_in[14];
    const float* bo1 = (const float*)d_in[15];
    const float* wo2 = (const float*)d_in[16];
    const float* bo2 = (const float*)d_in[17];
    const float* wm1 = (const float*)d_in[18];
    const float* bm1 = (const float*)d_in[19];
    const float* wm2 = (const float*)d_in[20];
    const float* bm2 = (const float*)d_in[21];
    const float* wg1 = (const float*)d_in[22];
    const float* bg1 = (const float*)d_in[23];
    const float* wg2 = (const float*)d_in[24];
    const float* bg2 = (const float*)d_in[25];

    float* out = (float*)d_out;
    float* gene_out = out;                  // [2048, 50]
    float* tok_out = out + 2048 * 50;       // [2048, 512]

    float* ws = (float*)d_ws;
    size_t o = 0;
    auto alloc = [&](size_t nf) {
        float* p = ws + o;
        o += nf;
        return p;
    };
    float* x_ln = alloc((size_t)2048 * 512);
    float* qkvb = alloc((size_t)2048 * 1536);
    float* q2 = alloc((size_t)16384 * 64);
    float* k2 = alloc((size_t)16384 * 64);
    float* qp = alloc((size_t)16384 * 512);
    float* kp = alloc((size_t)16384 * 512);
    float* gep = alloc((size_t)2048 * 512);
    float* edgeb = alloc((size_t)2048 * 16 * 128);
    float* logitsb = alloc((size_t)2048 * 128);
    float* scec = alloc((size_t)2048 * 640);
    float* buf1 = alloc((size_t)2048 * 512);
    float* buf2 = alloc((size_t)2048 * 2048);
    float* tok1 = alloc((size_t)2048 * 512);
    if (o * sizeof(float) > ws_size) return;  // ~145 MB required

    // 1. x_ln = LN(token_embs)
    act_ln_kernel<<<2048, 256, 0, stream>>>(x_ln, token_embs, 512, 0);
    // 2. qkv = x_ln @ w_qkv + b_qkv
    gemm_kernel<<<dim3(24, 32), 256, 0, stream>>>(x_ln, w_qkv, b_qkv, nullptr, qkvb, 2048, 512, 1536);
    // 3. repack q,k into [N*H, 64]
    repack_qk<<<4096, 256, 0, stream>>>(qkvb, q2, k2);
    // 4-6. attention fc1 decomposition pieces (no bias; ba1 added in logits_kernel)
    gemm_kernel<<<dim3(8, 256), 256, 0, stream>>>(q2, wa1, nullptr, nullptr, qp, 16384, 64, 512);
    gemm_kernel<<<dim3(8, 256), 256, 0, stream>>>(k2, wa1 + 64 * 512, nullptr, nullptr, kp, 16384, 64, 512);
    gemm_kernel<<<dim3(8, 32), 256, 0, stream>>>(gene_exp, wa1 + 144 * 512, nullptr, nullptr, gep, 2048, 50, 512);
    // 7. frame-averaged edge features
    edge_kernel<<<2048, 256, 0, stream>>>(coords, nbr, we1, be1, we2, be2, edgeb);
    // 8. fused attention-MLP logits
    logits_kernel<<<2048, 256, 0, stream>>>(qp, kp, gep, edgeb, nbr, wa1, ba1, wa2, ba2, logitsb);
    // 9. softmax + context aggregation
    smax_agg_kernel<<<2048, 256, 0, stream>>>(logitsb, qkvb, edgeb, nbr, scec);
    // 10. ctx = mlp2(scec, wo1, wo2); tok1 = token_embs + ctx
    gemm_kernel<<<dim3(8, 32), 256, 0, stream>>>(scec, wo1, bo1, nullptr, buf1, 2048, 640, 512);
    act_ln_kernel<<<2048, 256, 0, stream>>>(buf1, buf1, 512, 1);
    gemm_kernel<<<dim3(8, 32), 256, 0, stream>>>(buf1, wo2, bo2, token_embs, tok1, 2048, 512, 512);
    // 11. tok2 = tok1 + mlp2(tok1, wm1, wm2)  -> written to d_out tok section
    gemm_kernel<<<dim3(32, 32), 256, 0, stream>>>(tok1, wm1, bm1, nullptr, buf2, 2048, 512, 2048);
    act_ln_kernel<<<2048, 256, 0, stream>>>(buf2, buf2, 2048, 1);
    gemm_kernel<<<dim3(8, 32), 256, 0, stream>>>(buf2, wm2, bm2, tok1, tok_out, 2048, 2048, 512);
    // 12. gene_out = mlp2(tok2, wg1, wg2)
    gemm_kernel<<<dim3(8, 32), 256, 0, stream>>>(tok_out, wg1, bg1, nullptr, buf1, 2048, 512, 512);
    act_ln_kernel<<<2048, 256, 0, stream>>>(buf1, buf1, 512, 1);
    gemm_kernel<<<dim3(1, 32), 256, 0, stream>>>(buf1, wg2, bg2, nullptr, gene_out, 2048, 512, 50);
}

// Round 2
// 1423.088 us; speedup vs baseline: 9.0389x; 9.0389x over previous
//
#include <hip/hip_runtime.h>
#include <math.h>

// Problem constants
#define NN 2048
#define MM 16
#define DD 512
#define DE 128
#define HH 8
#define GG 50
#define DH 64
#define DEH 16

__device__ __forceinline__ float gelu_f(float x) {
    return 0.5f * x * (1.0f + erff(x * 0.70710678118654752440f));
}

__device__ __forceinline__ float wsum(float v) {
#pragma unroll
    for (int o = 32; o; o >>= 1) v += __shfl_xor(v, o, 64);
    return v;
}

// ---------------------------------------------------------------------------
// Row-wise (optional GELU) + LayerNorm, in-place capable. grid = rows, 256 thr
// ---------------------------------------------------------------------------
__global__ __launch_bounds__(256) void act_ln_kernel(float* __restrict__ y,
                                                     const float* __restrict__ x,
                                                     int C, int do_gelu) {
    int row = blockIdx.x, tid = threadIdx.x;
    int nv = C >> 8;  // C is 512 or 2048
    float v[8];
    float s = 0.f, ss = 0.f;
    for (int i = 0; i < nv; ++i) {
        float val = x[(size_t)row * C + tid + (i << 8)];
        if (do_gelu) val = gelu_f(val);
        v[i] = val;
        s += val;
        ss += val * val;
    }
    __shared__ float red[4][2];
    s = wsum(s);
    ss = wsum(ss);
    int wid = tid >> 6, lane = tid & 63;
    if (lane == 0) { red[wid][0] = s; red[wid][1] = ss; }
    __syncthreads();
    s = red[0][0] + red[1][0] + red[2][0] + red[3][0];
    ss = red[0][1] + red[1][1] + red[2][1] + red[3][1];
    float mean = s / (float)C;
    float var = ss / (float)C - mean * mean;
    float rs = rsqrtf(var + 1e-5f);
    for (int i = 0; i < nv; ++i)
        y[(size_t)row * C + tid + (i << 8)] = (v[i] - mean) * rs;
}

// ---------------------------------------------------------------------------
// Generic fp32 GEMM: C = A[Mr,K] @ W[K,Nc] (+bias[Nc]) (+resid[Mr,Nc])
// 64x64 tile, 256 threads, 4x4 per thread, K-step 16.
// ---------------------------------------------------------------------------
__global__ __launch_bounds__(256) void gemm_kernel(const float* __restrict__ A,
                                                   const float* __restrict__ W,
                                                   const float* __restrict__ bias,
                                                   const float* __restrict__ resid,
                                                   float* __restrict__ C,
                                                   int Mr, int K, int Nc) {
    __shared__ float Ast[16][68];
    __shared__ float Ws[16][68];
    int tid = threadIdx.x;
    int tx = tid & 15, ty = tid >> 4;
    int row0 = blockIdx.y << 6, col0 = blockIdx.x << 6;
    int r0 = ty << 2, c0 = tx << 2;
    float acc[4][4] = {};
    for (int k0 = 0; k0 < K; k0 += 16) {
#pragma unroll
        for (int i = 0; i < 4; ++i) {
            int idx = tid + (i << 8);
            int r = idx >> 4, kk = idx & 15;
            int gr = row0 + r, gk = k0 + kk;
            Ast[kk][r] = (gr < Mr && gk < K) ? A[(size_t)gr * K + gk] : 0.f;
            int kw = idx >> 6, c = idx & 63;
            int gc = col0 + c, gkw = k0 + kw;
            Ws[kw][c] = (gkw < K && gc < Nc) ? W[(size_t)gkw * Nc + gc] : 0.f;
        }
        __syncthreads();
#pragma unroll
        for (int kk = 0; kk < 16; ++kk) {
            float4 a4 = *(const float4*)&Ast[kk][r0];
            float4 b4 = *(const float4*)&Ws[kk][c0];
            float av[4] = {a4.x, a4.y, a4.z, a4.w};
            float bv[4] = {b4.x, b4.y, b4.z, b4.w};
#pragma unroll
            for (int i = 0; i < 4; ++i)
#pragma unroll
                for (int j = 0; j < 4; ++j) acc[i][j] = fmaf(av[i], bv[j], acc[i][j]);
        }
        __syncthreads();
    }
#pragma unroll
    for (int i = 0; i < 4; ++i) {
        int r = row0 + r0 + i;
        if (r >= Mr) continue;
#pragma unroll
        for (int j = 0; j < 4; ++j) {
            int c = col0 + c0 + j;
            if (c >= Nc) continue;
            float v = acc[i][j];
            if (bias) v += bias[c];
            if (resid) v += resid[(size_t)r * Nc + c];
            C[(size_t)r * Nc + c] = v;
        }
    }
}

// ---------------------------------------------------------------------------
// Repack q,k heads from qkv [N,1536] into [N*H, 64] row-major
// ---------------------------------------------------------------------------
__global__ __launch_bounds__(256) void repack_qk(const float* __restrict__ qkv,
                                                 float* __restrict__ q2,
                                                 float* __restrict__ k2) {
    int idx = blockIdx.x * 256 + threadIdx.x;  // < 16384*64
    int r = idx >> 6, t = idx & 63;
    int n = r >> 3, h = r & 7;
    q2[idx] = qkv[(size_t)n * 1536 + h * 64 + t];
    k2[idx] = qkv[(size_t)n * 1536 + 512 + h * 64 + t];
}

// ---------------------------------------------------------------------------
// Frame projections: per (n,m) compute PCA-frame projection + radial norm.
// 16 lanes per node (lane m = neighbor m), 16 nodes per 256-thread block.
// ---------------------------------------------------------------------------
__global__ __launch_bounds__(256) void proj_kernel(const float* __restrict__ coords,
                                                   const int* __restrict__ nbr,
                                                   float* __restrict__ projs,
                                                   float* __restrict__ rns) {
    int node = blockIdx.x * 16 + (threadIdx.x >> 4);
    int m = threadIdx.x & 15;
    float cx = coords[node * 2], cy = coords[node * 2 + 1];
    int j = nbr[node * 16 + m];
    float rx = coords[j * 2] - cx;
    float ry = coords[j * 2 + 1] - cy;
    float rn = sqrtf(rx * rx + ry * ry);
    float mx = rx, my = ry;
#pragma unroll
    for (int o = 8; o; o >>= 1) { mx += __shfl_xor(mx, o, 16); my += __shfl_xor(my, o, 16); }
    mx *= 0.0625f;
    my *= 0.0625f;
    float xcx = rx - mx, xcy = ry - my;
    float sxx = xcx * xcx, sxy = xcx * xcy, syy = xcy * xcy;
#pragma unroll
    for (int o = 8; o; o >>= 1) {
        sxx += __shfl_xor(sxx, o, 16);
        sxy += __shfl_xor(sxy, o, 16);
        syy += __shfl_xor(syy, o, 16);
    }
    // closed-form 2x2 symmetric eigendecomposition (ascending order), f64
    double a = (double)sxx, b = (double)sxy, c = (double)syy;
    double diff = 0.5 * (a - c);
    double disc = sqrt(diff * diff + b * b);
    double l2 = 0.5 * (a + c) + disc;
    double v2x = b, v2y = l2 - a;
    double nn2 = sqrt(v2x * v2x + v2y * v2y);
    if (nn2 < 1e-30) { v2x = (a >= c) ? 1.0 : 0.0; v2y = 1.0 - v2x; nn2 = 1.0; }
    v2x /= nn2;
    v2y /= nn2;
    double v1x = -v2y, v1y = v2x;  // eigenvector of smaller eigenvalue
    int row = node * 16 + m;
    projs[row * 2] = (float)((double)xcx * v1x + (double)xcy * v1y);
    projs[row * 2 + 1] = (float)((double)xcx * v2x + (double)xcy * v2y);
    rns[row] = rn;
}

// ---------------------------------------------------------------------------
// Frame MLP stage 1: u[row,c] = 0.25 * sum_f LN(gelu([frame_f, rn] @ we1 + be1))
// One wave per (n,m) row, 2 channels per lane. No LDS, no spills.
// ---------------------------------------------------------------------------
__global__ __launch_bounds__(256) void frame_mlp1_kernel(const float* __restrict__ projs,
                                                         const float* __restrict__ rns,
                                                         const float* __restrict__ we1,
                                                         const float* __restrict__ be1,
                                                         float* __restrict__ u) {
    int row = blockIdx.x * 4 + (threadIdx.x >> 6);
    int lane = threadIdx.x & 63;
    float px = projs[row * 2], py = projs[row * 2 + 1], rn = rns[row];
    int c0 = lane, c1 = lane + 64;
    float w10a = we1[c0], w11a = we1[128 + c0], w12a = we1[256 + c0], b1a = be1[c0];
    float w10b = we1[c1], w11b = we1[128 + c1], w12b = we1[256 + c1], b1b = be1[c1];
    float acc0 = 0.f, acc1 = 0.f;
    const float opsx[4] = {-1.f, -1.f, 1.f, 1.f};
    const float opsy[4] = {-1.f, 1.f, -1.f, 1.f};
#pragma unroll
    for (int f = 0; f < 4; ++f) {
        float fx = opsx[f] * px, fy = opsy[f] * py;
        float h0 = gelu_f(fmaf(fx, w10a, fmaf(fy, w11a, fmaf(rn, w12a, b1a))));
        float h1 = gelu_f(fmaf(fx, w10b, fmaf(fy, w11b, fmaf(rn, w12b, b1b))));
        float s = wsum(h0 + h1);
        float ss = wsum(fmaf(h0, h0, h1 * h1));
        float mean = s * (1.f / 128.f);
        float var = ss * (1.f / 128.f) - mean * mean;
        float rs = rsqrtf(var + 1e-5f);
        acc0 += (h0 - mean) * rs;
        acc1 += (h1 - mean) * rs;
    }
    u[(size_t)row * 128 + c0] = 0.25f * acc0;
    u[(size_t)row * 128 + c1] = 0.25f * acc1;
}

// ---------------------------------------------------------------------------
// Fused attention-MLP logits. Block per n; wave per (m,h) row.
// val[c] = qp[n,h,c] + kp[j,h,c] + gep[j,c]-gep[n,c] + ba1[c] + edge_h@wa1_e
// logit = LN(gelu(val)) . wa2 + ba2   (LN+dot via 3 wave reductions, no store)
// ---------------------------------------------------------------------------
__global__ __launch_bounds__(256) void logits_kernel(const float* __restrict__ qp,
                                                     const float* __restrict__ kp,
                                                     const float* __restrict__ gep,
                                                     const float* __restrict__ edge,
                                                     const int* __restrict__ nbr,
                                                     const float* __restrict__ wa1,
                                                     const float* __restrict__ ba1,
                                                     const float* __restrict__ wa2,
                                                     const float* __restrict__ ba2,
                                                     float* __restrict__ logits) {
    __shared__ float wes[16 * 512];
    __shared__ float wa2s[512], ba1s[512], gepn[512];
    __shared__ float edl[16 * 128];
    __shared__ int jn[16];
    int n = blockIdx.x, tid = threadIdx.x;
    for (int i = tid; i < 16 * 512; i += 256) wes[i] = wa1[128 * 512 + i];
    for (int i = tid; i < 512; i += 256) {
        wa2s[i] = wa2[i];
        ba1s[i] = ba1[i];
        gepn[i] = gep[(size_t)n * 512 + i];
    }
    for (int i = tid; i < 16 * 128; i += 256) edl[i] = edge[(size_t)n * 2048 + i];
    if (tid < 16) jn[tid] = nbr[n * 16 + tid];
    __syncthreads();
    int wid = tid >> 6, lane = tid & 63;
    float sw = 0.f;
#pragma unroll
    for (int i = 0; i < 8; ++i) sw += wa2s[lane + 64 * i];
    sw = wsum(sw);
    float ba2v = ba2[0];
    for (int r = wid; r < 128; r += 4) {
        int m = r >> 3, h = r & 7;
        int j = jn[m];
        const float* qrow = qp + ((size_t)n * 8 + h) * 512;
        const float* krow = kp + ((size_t)j * 8 + h) * 512;
        const float* grow = gep + (size_t)j * 512;
        const float* ew = edl + m * 128 + h * 16;
        float s = 0.f, ss = 0.f, sd = 0.f;
#pragma unroll
        for (int i = 0; i < 8; ++i) {
            int c = lane + 64 * i;
            float val = qrow[c] + krow[c] + (grow[c] - gepn[c]) + ba1s[c];
#pragma unroll
            for (int t = 0; t < 16; ++t) val = fmaf(ew[t], wes[t * 512 + c], val);
            float gv = gelu_f(val);
            s += gv;
            ss += gv * gv;
            sd = fmaf(gv, wa2s[c], sd);
        }
        s = wsum(s);
        ss = wsum(ss);
        sd = wsum(sd);
        if (lane == 0) {
            float mean = s * (1.f / 512.f);
            float var = ss * (1.f / 512.f) - mean * mean;
            logits[((size_t)n * 8 + h) * 16 + m] = (sd - mean * sw) * rsqrtf(var + 1e-5f) + ba2v;
        }
    }
}

// ---------------------------------------------------------------------------
// Softmax over M per (n,h) + context aggregation -> scec [N, 640] = [sc | ec]
// ---------------------------------------------------------------------------
__global__ __launch_bounds__(256) void smax_agg_kernel(const float* __restrict__ logits,
                                                       const float* __restrict__ qkv,
                                                       const float* __restrict__ edge,
                                                       const int* __restrict__ nbr,
                                                       float* __restrict__ scec) {
    __shared__ float attn[128];
    __shared__ int jn[16];
    int n = blockIdx.x, tid = threadIdx.x;
    if (tid < 16) jn[tid] = nbr[n * 16 + tid];
    if (tid < 128) {
        float lg = logits[(size_t)n * 128 + tid];
        float mx = lg;
#pragma unroll
        for (int o = 8; o; o >>= 1) mx = fmaxf(mx, __shfl_xor(mx, o, 16));
        float e = expf(lg - mx);
        float se = e;
#pragma unroll
        for (int o = 8; o; o >>= 1) se += __shfl_xor(se, o, 16);
        attn[tid] = e / se;
    }
    __syncthreads();
    for (int c = tid; c < 640; c += 256) {
        float acc = 0.f;
        if (c < 512) {
            int h = c >> 6, t = c & 63;
#pragma unroll
            for (int m = 0; m < 16; ++m)
                acc = fmaf(attn[h * 16 + m], qkv[(size_t)jn[m] * 1536 + 1024 + h * 64 + t], acc);
        } else {
            int d = c - 512, h = d >> 4, t = d & 15;
#pragma unroll
            for (int m = 0; m < 16; ++m)
                acc = fmaf(attn[h * 16 + m], edge[((size_t)n * 16 + m) * 128 + h * 16 + t], acc);
        }
        scec[(size_t)n * 640 + c] = acc;
    }
}

// ---------------------------------------------------------------------------
extern "C" void kernel_launch(void* const* d_in, const int* in_sizes, int n_in,
                              void* d_out, int out_size, void* d_ws, size_t ws_size,
                              hipStream_t stream) {
    const float* gene_exp = (const float*)d_in[0];
    const float* token_embs = (const float*)d_in[1];
    const float* coords = (const float*)d_in[2];
    const int* nbr = (const int*)d_in[3];
    const float* w_qkv = (const float*)d_in[4];
    const float* b_qkv = (const float*)d_in[5];
    const float* wa1 = (const float*)d_in[6];
    const float* ba1 = (const float*)d_in[7];
    const float* wa2 = (const float*)d_in[8];
    const float* ba2 = (const float*)d_in[9];
    const float* we1 = (const float*)d_in[10];
    const float* be1 = (const float*)d_in[11];
    const float* we2 = (const float*)d_in[12];
    const float* be2 = (const float*)d_in[13];
    const float* wo1 = (const float*)d_in[14];
    const float* bo1 = (const float*)d_in[15];
    const float* wo2 = (const float*)d_in[16];
    const float* bo2 = (const float*)d_in[17];
    const float* wm1 = (const float*)d_in[18];
    const float* bm1 = (const float*)d_in[19];
    const float* wm2 = (const float*)d_in[20];
    const float* bm2 = (const float*)d_in[21];
    const float* wg1 = (const float*)d_in[22];
    const float* bg1 = (const float*)d_in[23];
    const float* wg2 = (const float*)d_in[24];
    const float* bg2 = (const float*)d_in[25];

    float* out = (float*)d_out;
    float* gene_out = out;                  // [2048, 50]
    float* tok_out = out + 2048 * 50;       // [2048, 512]

    float* ws = (float*)d_ws;
    size_t o = 0;
    auto alloc = [&](size_t nf) {
        float* p = ws + o;
        o += nf;
        return p;
    };
    float* x_ln = alloc((size_t)2048 * 512);
    float* qkvb = alloc((size_t)2048 * 1536);
    float* q2 = alloc((size_t)16384 * 64);
    float* k2 = alloc((size_t)16384 * 64);
    float* qp = alloc((size_t)16384 * 512);
    float* kp = alloc((size_t)16384 * 512);
    float* gep = alloc((size_t)2048 * 512);
    float* edgeb = alloc((size_t)2048 * 16 * 128);
    float* logitsb = alloc((size_t)2048 * 128);
    float* scec = alloc((size_t)2048 * 640);
    float* buf1 = alloc((size_t)2048 * 512);
    float* buf2 = alloc((size_t)2048 * 2048);
    float* tok1 = alloc((size_t)2048 * 512);
    if (o * sizeof(float) > ws_size) return;  // ~145 MB required
    // aliases (lifetimes do not overlap their hosts):
    float* u = buf2;              // [32768,128], dead before step 11 uses buf2
    float* projs = buf1;          // [32768,2],  dead before step 10 uses buf1
    float* rns = buf1 + 65536;    // [32768]

    // 1. x_ln = LN(token_embs)
    act_ln_kernel<<<2048, 256, 0, stream>>>(x_ln, token_embs, 512, 0);
    // 2. qkv = x_ln @ w_qkv + b_qkv
    gemm_kernel<<<dim3(24, 32), 256, 0, stream>>>(x_ln, w_qkv, b_qkv, nullptr, qkvb, 2048, 512, 1536);
    // 3. repack q,k into [N*H, 64]
    repack_qk<<<4096, 256, 0, stream>>>(qkvb, q2, k2);
    // 4-6. attention fc1 decomposition pieces (no bias; ba1 added in logits_kernel)
    gemm_kernel<<<dim3(8, 256), 256, 0, stream>>>(q2, wa1, nullptr, nullptr, qp, 16384, 64, 512);
    gemm_kernel<<<dim3(8, 256), 256, 0, stream>>>(k2, wa1 + 64 * 512, nullptr, nullptr, kp, 16384, 64, 512);
    gemm_kernel<<<dim3(8, 32), 256, 0, stream>>>(gene_exp, wa1 + 144 * 512, nullptr, nullptr, gep, 2048, 50, 512);
    // 7. frame-averaged edge features: proj -> per-frame MLP1 (+LN, sum) -> @we2
    proj_kernel<<<128, 256, 0, stream>>>(coords, nbr, projs, rns);
    frame_mlp1_kernel<<<8192, 256, 0, stream>>>(projs, rns, we1, be1, u);
    gemm_kernel<<<dim3(2, 512), 256, 0, stream>>>(u, we2, be2, nullptr, edgeb, 32768, 128, 128);
    // 8. fused attention-MLP logits
    logits_kernel<<<2048, 256, 0, stream>>>(qp, kp, gep, edgeb, nbr, wa1, ba1, wa2, ba2, logitsb);
    // 9. softmax + context aggregation
    smax_agg_kernel<<<2048, 256, 0, stream>>>(logitsb, qkvb, edgeb, nbr, scec);
    // 10. ctx = mlp2(scec, wo1, wo2); tok1 = token_embs + ctx
    gemm_kernel<<<dim3(8, 32), 256, 0, stream>>>(scec, wo1, bo1, nullptr, buf1, 2048, 640, 512);
    act_ln_kernel<<<2048, 256, 0, stream>>>(buf1, buf1, 512, 1);
    gemm_kernel<<<dim3(8, 32), 256, 0, stream>>>(buf1, wo2, bo2, token_embs, tok1, 2048, 512, 512);
    // 11. tok2 = tok1 + mlp2(tok1, wm1, wm2)  -> written to d_out tok section
    gemm_kernel<<<dim3(32, 32), 256, 0, stream>>>(tok1, wm1, bm1, nullptr, buf2, 2048, 512, 2048);
    act_ln_kernel<<<2048, 256, 0, stream>>>(buf2, buf2, 2048, 1);
    gemm_kernel<<<dim3(8, 32), 256, 0, stream>>>(buf2, wm2, bm2, tok1, tok_out, 2048, 2048, 512);
    // 12. gene_out = mlp2(tok2, wg1, wg2)
    gemm_kernel<<<dim3(8, 32), 256, 0, stream>>>(tok_out, wg1, bg1, nullptr, buf1, 2048, 512, 512);
    act_ln_kernel<<<2048, 256, 0, stream>>>(buf1, buf1, 512, 1);
    gemm_kernel<<<dim3(1, 32), 256, 0, stream>>>(buf1, wg2, bg2, nullptr, gene_out, 2048, 512, 50);
}

// Round 3
// 608.647 us; speedup vs baseline: 21.1339x; 2.3381x over previous
//
#include <hip/hip_runtime.h>
#include <math.h>

// Problem constants
#define NN 2048
#define MM 16
#define DD 512
#define DE 128
#define HH 8
#define GG 50
#define DH 64
#define DEH 16

typedef __attribute__((ext_vector_type(8))) short bf8_t;   // 8 bf16 = 4 VGPRs
typedef __attribute__((ext_vector_type(4))) float f4_t;    // MFMA accumulator

__device__ __forceinline__ float gelu_f(float x) {
    return 0.5f * x * (1.0f + erff(x * 0.70710678118654752440f));
}

__device__ __forceinline__ float wsum(float v) {
#pragma unroll
    for (int o = 32; o; o >>= 1) v += __shfl_xor(v, o, 64);
    return v;
}

__device__ __forceinline__ unsigned short f2bf(float x) {
    union { float f; unsigned int u; } v;
    v.f = x;
    unsigned int r = v.u + 0x7FFFu + ((v.u >> 16) & 1u);  // RNE
    return (unsigned short)(r >> 16);
}

__device__ __forceinline__ float bfu(unsigned int u) {
    union { unsigned int x; float f; } v;
    v.x = u;
    return v.f;
}
// packed u32 of 2 bf16 -> floats
#define BF_LO(u) bfu((u) << 16)
#define BF_HI(u) bfu((u) & 0xFFFF0000u)

// ---------------------------------------------------------------------------
// Row-wise (optional GELU) + LayerNorm. Writes fp32 and/or bf16 output.
// ---------------------------------------------------------------------------
__global__ __launch_bounds__(256) void act_ln_kernel(float* __restrict__ outF,
                                                     unsigned short* __restrict__ outB,
                                                     const float* __restrict__ x,
                                                     int C, int do_gelu) {
    int row = blockIdx.x, tid = threadIdx.x;
    int nv = C >> 8;  // C is 512 or 2048
    float v[8];
    float s = 0.f, ss = 0.f;
    for (int i = 0; i < nv; ++i) {
        float val = x[(size_t)row * C + tid + (i << 8)];
        if (do_gelu) val = gelu_f(val);
        v[i] = val;
        s += val;
        ss += val * val;
    }
    __shared__ float red[4][2];
    s = wsum(s);
    ss = wsum(ss);
    int wid = tid >> 6, lane = tid & 63;
    if (lane == 0) { red[wid][0] = s; red[wid][1] = ss; }
    __syncthreads();
    s = red[0][0] + red[1][0] + red[2][0] + red[3][0];
    ss = red[0][1] + red[1][1] + red[2][1] + red[3][1];
    float mean = s / (float)C;
    float var = ss / (float)C - mean * mean;
    float rs = rsqrtf(var + 1e-5f);
    for (int i = 0; i < nv; ++i) {
        float y = (v[i] - mean) * rs;
        size_t idx = (size_t)row * C + tid + (i << 8);
        if (outF) outF[idx] = y;
        if (outB) outB[idx] = f2bf(y);
    }
}

// ---------------------------------------------------------------------------
// Transpose-cast: W [K,N] fp32 -> Wt [N,K] bf16. 32x32 LDS tile.
// ---------------------------------------------------------------------------
__global__ __launch_bounds__(256) void tcast_kernel(const float* __restrict__ W,
                                                    unsigned short* __restrict__ Wt,
                                                    int K, int N) {
    __shared__ float tile[32][33];
    int tx = threadIdx.x & 31, ty = threadIdx.x >> 5;
    int n0 = blockIdx.x * 32, k0 = blockIdx.y * 32;
#pragma unroll
    for (int p = 0; p < 4; ++p) {
        int k = k0 + ty + p * 8;
        tile[ty + p * 8][tx] = (k < K && n0 + tx < N) ? W[(size_t)k * N + n0 + tx] : 0.f;
    }
    __syncthreads();
#pragma unroll
    for (int p = 0; p < 4; ++p) {
        int n = n0 + ty + p * 8;
        if (n < N && k0 + tx < K) Wt[(size_t)n * K + k0 + tx] = f2bf(tile[tx][ty + p * 8]);
    }
}

// ---------------------------------------------------------------------------
// bf16 MFMA GEMM: out = A[M,K](bf16) @ Bt[N,K](bf16)^T (+bias) (+resid)
// 128x128 tile, 4 waves (2x2), each wave 64x64 = 4x4 frags of 16x16.
// K-step 64. LDS XOR-swizzled via pre-swizzled staging content:
//   row r of LDS holds its 8 16B-chunks in order chunk^(r&7), so fragment
//   reads at slot^(r&7) are 2-way-max on banks (free).
// Requires: 128|M, 128|N, 64|K. No bounds checks.
// ---------------------------------------------------------------------------
__global__ __launch_bounds__(256) void gemm_bf16_kernel(
    const unsigned short* __restrict__ A, const unsigned short* __restrict__ Bt,
    const float* __restrict__ bias, const float* __restrict__ resid,
    float* __restrict__ outF, unsigned short* __restrict__ outB,
    int M, int K, int N) {
    __shared__ unsigned short As[128 * 64];
    __shared__ unsigned short Bs[128 * 64];
    int tid = threadIdx.x;
    int lane = tid & 63;
    int w = tid >> 6;
    int wr = w >> 1, wc = w & 1;
    int row0 = blockIdx.y * 128, col0 = blockIdx.x * 128;
    f4_t acc[4][4];
#pragma unroll
    for (int a = 0; a < 4; ++a)
#pragma unroll
        for (int b = 0; b < 4; ++b) {
            acc[a][b][0] = 0.f; acc[a][b][1] = 0.f;
            acc[a][b][2] = 0.f; acc[a][b][3] = 0.f;
        }

    for (int kt = 0; kt < K; kt += 64) {
        __syncthreads();
#pragma unroll
        for (int p = 0; p < 4; ++p) {
            int id = p * 256 + tid;        // 1024 chunks of 16B
            int r = id >> 3, cch = id & 7;
            int kc = cch ^ (r & 7);        // swizzled source chunk
            uint4 av = *(const uint4*)(A + (size_t)(row0 + r) * K + kt + kc * 8);
            *(uint4*)((char*)As + id * 16) = av;
            uint4 bv = *(const uint4*)(Bt + (size_t)(col0 + r) * K + kt + kc * 8);
            *(uint4*)((char*)Bs + id * 16) = bv;
        }
        __syncthreads();
#pragma unroll
        for (int kk = 0; kk < 2; ++kk) {
            bf8_t af[4], bfr[4];
            int kslot = kk * 4 + (lane >> 4);
#pragma unroll
            for (int mi = 0; mi < 4; ++mi) {
                int r = wr * 64 + mi * 16 + (lane & 15);
                af[mi] = *(const bf8_t*)((char*)As + r * 128 + ((kslot ^ (r & 7)) * 16));
            }
#pragma unroll
            for (int ni = 0; ni < 4; ++ni) {
                int r = wc * 64 + ni * 16 + (lane & 15);
                bfr[ni] = *(const bf8_t*)((char*)Bs + r * 128 + ((kslot ^ (r & 7)) * 16));
            }
#pragma unroll
            for (int mi = 0; mi < 4; ++mi)
#pragma unroll
                for (int ni = 0; ni < 4; ++ni)
                    acc[mi][ni] = __builtin_amdgcn_mfma_f32_16x16x32_bf16(
                        af[mi], bfr[ni], acc[mi][ni], 0, 0, 0);
        }
    }
    // epilogue: D row = A-row (lane>>4)*4+j, col = B-col (lane&15)
    int cr = lane >> 4, cc = lane & 15;
#pragma unroll
    for (int mi = 0; mi < 4; ++mi)
#pragma unroll
        for (int ni = 0; ni < 4; ++ni) {
            int col = col0 + wc * 64 + ni * 16 + cc;
            float bv = bias ? bias[col] : 0.f;
#pragma unroll
            for (int j = 0; j < 4; ++j) {
                int row = row0 + wr * 64 + mi * 16 + cr * 4 + j;
                float v = acc[mi][ni][j] + bv;
                if (resid) v += resid[(size_t)row * N + col];
                if (outF) outF[(size_t)row * N + col] = v;
                if (outB) outB[(size_t)row * N + col] = f2bf(v);
            }
        }
}

// ---------------------------------------------------------------------------
// Generic fp32 GEMM (kept for K=50 / N=50 cases): C = A@W (+bias)
// ---------------------------------------------------------------------------
__global__ __launch_bounds__(256) void gemm_kernel(const float* __restrict__ A,
                                                   const float* __restrict__ W,
                                                   const float* __restrict__ bias,
                                                   const float* __restrict__ resid,
                                                   float* __restrict__ C,
                                                   int Mr, int K, int Nc) {
    __shared__ float Ast[16][68];
    __shared__ float Ws[16][68];
    int tid = threadIdx.x;
    int tx = tid & 15, ty = tid >> 4;
    int row0 = blockIdx.y << 6, col0 = blockIdx.x << 6;
    int r0 = ty << 2, c0 = tx << 2;
    float acc[4][4] = {};
    for (int k0 = 0; k0 < K; k0 += 16) {
#pragma unroll
        for (int i = 0; i < 4; ++i) {
            int idx = tid + (i << 8);
            int r = idx >> 4, kk = idx & 15;
            int gr = row0 + r, gk = k0 + kk;
            Ast[kk][r] = (gr < Mr && gk < K) ? A[(size_t)gr * K + gk] : 0.f;
            int kw = idx >> 6, c = idx & 63;
            int gc = col0 + c, gkw = k0 + kw;
            Ws[kw][c] = (gkw < K && gc < Nc) ? W[(size_t)gkw * Nc + gc] : 0.f;
        }
        __syncthreads();
#pragma unroll
        for (int kk = 0; kk < 16; ++kk) {
            float4 a4 = *(const float4*)&Ast[kk][r0];
            float4 b4 = *(const float4*)&Ws[kk][c0];
            float av[4] = {a4.x, a4.y, a4.z, a4.w};
            float bv[4] = {b4.x, b4.y, b4.z, b4.w};
#pragma unroll
            for (int i = 0; i < 4; ++i)
#pragma unroll
                for (int j = 0; j < 4; ++j) acc[i][j] = fmaf(av[i], bv[j], acc[i][j]);
        }
        __syncthreads();
    }
#pragma unroll
    for (int i = 0; i < 4; ++i) {
        int r = row0 + r0 + i;
        if (r >= Mr) continue;
#pragma unroll
        for (int j = 0; j < 4; ++j) {
            int c = col0 + c0 + j;
            if (c >= Nc) continue;
            float v = acc[i][j];
            if (bias) v += bias[c];
            if (resid) v += resid[(size_t)r * Nc + c];
            C[(size_t)r * Nc + c] = v;
        }
    }
}

// ---------------------------------------------------------------------------
// Repack q,k heads from qkv [N,1536] fp32 into bf16 [N*H, 64] row-major
// ---------------------------------------------------------------------------
__global__ __launch_bounds__(256) void repack_qk(const float* __restrict__ qkv,
                                                 unsigned short* __restrict__ q2,
                                                 unsigned short* __restrict__ k2) {
    int idx = blockIdx.x * 256 + threadIdx.x;  // < 16384*64
    int r = idx >> 6, t = idx & 63;
    int n = r >> 3, h = r & 7;
    q2[idx] = f2bf(qkv[(size_t)n * 1536 + h * 64 + t]);
    k2[idx] = f2bf(qkv[(size_t)n * 1536 + 512 + h * 64 + t]);
}

// ---------------------------------------------------------------------------
// Frame projections: per (n,m) PCA-frame projection + radial norm.
// ---------------------------------------------------------------------------
__global__ __launch_bounds__(256) void proj_kernel(const float* __restrict__ coords,
                                                   const int* __restrict__ nbr,
                                                   float* __restrict__ projs,
                                                   float* __restrict__ rns) {
    int node = blockIdx.x * 16 + (threadIdx.x >> 4);
    int m = threadIdx.x & 15;
    float cx = coords[node * 2], cy = coords[node * 2 + 1];
    int j = nbr[node * 16 + m];
    float rx = coords[j * 2] - cx;
    float ry = coords[j * 2 + 1] - cy;
    float rn = sqrtf(rx * rx + ry * ry);
    float mx = rx, my = ry;
#pragma unroll
    for (int o = 8; o; o >>= 1) { mx += __shfl_xor(mx, o, 16); my += __shfl_xor(my, o, 16); }
    mx *= 0.0625f;
    my *= 0.0625f;
    float xcx = rx - mx, xcy = ry - my;
    float sxx = xcx * xcx, sxy = xcx * xcy, syy = xcy * xcy;
#pragma unroll
    for (int o = 8; o; o >>= 1) {
        sxx += __shfl_xor(sxx, o, 16);
        sxy += __shfl_xor(sxy, o, 16);
        syy += __shfl_xor(syy, o, 16);
    }
    double a = (double)sxx, b = (double)sxy, c = (double)syy;
    double diff = 0.5 * (a - c);
    double disc = sqrt(diff * diff + b * b);
    double l2 = 0.5 * (a + c) + disc;
    double v2x = b, v2y = l2 - a;
    double nn2 = sqrt(v2x * v2x + v2y * v2y);
    if (nn2 < 1e-30) { v2x = (a >= c) ? 1.0 : 0.0; v2y = 1.0 - v2x; nn2 = 1.0; }
    v2x /= nn2;
    v2y /= nn2;
    double v1x = -v2y, v1y = v2x;  // eigenvector of smaller eigenvalue
    int row = node * 16 + m;
    projs[row * 2] = (float)((double)xcx * v1x + (double)xcy * v1y);
    projs[row * 2 + 1] = (float)((double)xcx * v2x + (double)xcy * v2y);
    rns[row] = rn;
}

// ---------------------------------------------------------------------------
// Frame MLP stage 1 -> u bf16: u[row,c] = 0.25*sum_f LN(gelu([frame,rn]@we1+be1))
// ---------------------------------------------------------------------------
__global__ __launch_bounds__(256) void frame_mlp1_kernel(const float* __restrict__ projs,
                                                         const float* __restrict__ rns,
                                                         const float* __restrict__ we1,
                                                         const float* __restrict__ be1,
                                                         unsigned short* __restrict__ u) {
    int row = blockIdx.x * 4 + (threadIdx.x >> 6);
    int lane = threadIdx.x & 63;
    float px = projs[row * 2], py = projs[row * 2 + 1], rn = rns[row];
    int c0 = lane, c1 = lane + 64;
    float w10a = we1[c0], w11a = we1[128 + c0], w12a = we1[256 + c0], b1a = be1[c0];
    float w10b = we1[c1], w11b = we1[128 + c1], w12b = we1[256 + c1], b1b = be1[c1];
    float acc0 = 0.f, acc1 = 0.f;
    const float opsx[4] = {-1.f, -1.f, 1.f, 1.f};
    const float opsy[4] = {-1.f, 1.f, -1.f, 1.f};
#pragma unroll
    for (int f = 0; f < 4; ++f) {
        float fx = opsx[f] * px, fy = opsy[f] * py;
        float h0 = gelu_f(fmaf(fx, w10a, fmaf(fy, w11a, fmaf(rn, w12a, b1a))));
        float h1 = gelu_f(fmaf(fx, w10b, fmaf(fy, w11b, fmaf(rn, w12b, b1b))));
        float s = wsum(h0 + h1);
        float ss = wsum(fmaf(h0, h0, h1 * h1));
        float mean = s * (1.f / 128.f);
        float var = ss * (1.f / 128.f) - mean * mean;
        float rs = rsqrtf(var + 1e-5f);
        acc0 += (h0 - mean) * rs;
        acc1 += (h1 - mean) * rs;
    }
    u[(size_t)row * 128 + c0] = f2bf(0.25f * acc0);
    u[(size_t)row * 128 + c1] = f2bf(0.25f * acc1);
}

// ---------------------------------------------------------------------------
// Fused attention-MLP logits. LDS-free. Block per n, wave per h in {w, w+4}.
// c-mapping: lane owns channels c = lane*8 .. lane*8+7 (vectorized loads).
// Edge weights (wa1 rows 128..143, h-independent) live in 128 VGPRs/lane.
// Edge values ew[n,m,t] are wave-uniform -> scalar loads feeding v_fmac v,s,v.
// ---------------------------------------------------------------------------
__global__ __launch_bounds__(256) void logits_kernel(
    const unsigned short* __restrict__ qp, const unsigned short* __restrict__ kp,
    const float* __restrict__ gep, const float* __restrict__ edge,
    const int* __restrict__ nbr, const float* __restrict__ wa1,
    const float* __restrict__ ba1, const float* __restrict__ wa2,
    const float* __restrict__ ba2, float* __restrict__ logits) {
    int n = blockIdx.x;
    int tid = threadIdx.x;
    int w = __builtin_amdgcn_readfirstlane(tid >> 6);  // wave id, provably uniform
    int lane = tid & 63;
    int c0 = lane * 8;

    float wt[16][8];
#pragma unroll
    for (int t = 0; t < 16; ++t) {
        const float* wr = wa1 + (size_t)(128 + t) * 512 + c0;
        float4 p = *(const float4*)wr;
        float4 q = *(const float4*)(wr + 4);
        wt[t][0] = p.x; wt[t][1] = p.y; wt[t][2] = p.z; wt[t][3] = p.w;
        wt[t][4] = q.x; wt[t][5] = q.y; wt[t][6] = q.z; wt[t][7] = q.w;
    }
    float basec[8], wa2v[8];
    {
        float4 p = *(const float4*)(ba1 + c0), q = *(const float4*)(ba1 + c0 + 4);
        float4 g1 = *(const float4*)(gep + (size_t)n * 512 + c0);
        float4 g2 = *(const float4*)(gep + (size_t)n * 512 + c0 + 4);
        basec[0] = p.x - g1.x; basec[1] = p.y - g1.y; basec[2] = p.z - g1.z; basec[3] = p.w - g1.w;
        basec[4] = q.x - g2.x; basec[5] = q.y - g2.y; basec[6] = q.z - g2.z; basec[7] = q.w - g2.w;
        float4 a1 = *(const float4*)(wa2 + c0), a2 = *(const float4*)(wa2 + c0 + 4);
        wa2v[0] = a1.x; wa2v[1] = a1.y; wa2v[2] = a1.z; wa2v[3] = a1.w;
        wa2v[4] = a2.x; wa2v[5] = a2.y; wa2v[6] = a2.z; wa2v[7] = a2.w;
    }
    float swv = 0.f;
#pragma unroll
    for (int i = 0; i < 8; ++i) swv += wa2v[i];
    float sw = wsum(swv);
    float ba2v = ba2[0];

    for (int hh = 0; hh < 2; ++hh) {
        int h = w + hh * 4;  // uniform
        float qv[8];
        {
            uint4 q4 = *(const uint4*)(qp + ((size_t)n * 8 + h) * 512 + c0);
            qv[0] = BF_LO(q4.x) + basec[0]; qv[1] = BF_HI(q4.x) + basec[1];
            qv[2] = BF_LO(q4.y) + basec[2]; qv[3] = BF_HI(q4.y) + basec[3];
            qv[4] = BF_LO(q4.z) + basec[4]; qv[5] = BF_HI(q4.z) + basec[5];
            qv[6] = BF_LO(q4.w) + basec[6]; qv[7] = BF_HI(q4.w) + basec[7];
        }
#pragma unroll 2
        for (int m = 0; m < 16; ++m) {
            int j = nbr[n * 16 + m];                                      // uniform -> s_load
            const float* ew = edge + ((size_t)n * 16 + m) * 128 + h * 16; // uniform ptr
            const unsigned short* kr = kp + ((size_t)j * 8 + h) * 512 + c0;
            const float* gr = gep + (size_t)j * 512 + c0;
            uint4 k4 = *(const uint4*)kr;
            float4 g1 = *(const float4*)gr, g2 = *(const float4*)(gr + 4);
            float val[8];
            val[0] = qv[0] + BF_LO(k4.x) + g1.x; val[1] = qv[1] + BF_HI(k4.x) + g1.y;
            val[2] = qv[2] + BF_LO(k4.y) + g1.z; val[3] = qv[3] + BF_HI(k4.y) + g1.w;
            val[4] = qv[4] + BF_LO(k4.z) + g2.x; val[5] = qv[5] + BF_HI(k4.z) + g2.y;
            val[6] = qv[6] + BF_LO(k4.w) + g2.z; val[7] = qv[7] + BF_HI(k4.w) + g2.w;
#pragma unroll
            for (int t = 0; t < 16; ++t) {
                float e = ew[t];  // scalar (SGPR) load, L2-resident
#pragma unroll
                for (int i = 0; i < 8; ++i) val[i] = fmaf(e, wt[t][i], val[i]);
            }
            float s = 0.f, ss = 0.f, sd = 0.f;
#pragma unroll
            for (int i = 0; i < 8; ++i) {
                float gv = gelu_f(val[i]);
                s += gv;
                ss += gv * gv;
                sd = fmaf(gv, wa2v[i], sd);
            }
            s = wsum(s);
            ss = wsum(ss);
            sd = wsum(sd);
            if (lane == 0) {
                float mean = s * (1.f / 512.f);
                float var = ss * (1.f / 512.f) - mean * mean;
                logits[((size_t)n * 8 + h) * 16 + m] = (sd - mean * sw) * rsqrtf(var + 1e-5f) + ba2v;
            }
        }
    }
}

// ---------------------------------------------------------------------------
// Softmax over M per (n,h) + context aggregation -> scec bf16 [N,640]
// ---------------------------------------------------------------------------
__global__ __launch_bounds__(256) void smax_agg_kernel(const float* __restrict__ logits,
                                                       const float* __restrict__ qkv,
                                                       const float* __restrict__ edge,
                                                       const int* __restrict__ nbr,
                                                       unsigned short* __restrict__ scec) {
    __shared__ float attn[128];
    __shared__ int jn[16];
    int n = blockIdx.x, tid = threadIdx.x;
    if (tid < 16) jn[tid] = nbr[n * 16 + tid];
    if (tid < 128) {
        float lg = logits[(size_t)n * 128 + tid];
        float mx = lg;
#pragma unroll
        for (int o = 8; o; o >>= 1) mx = fmaxf(mx, __shfl_xor(mx, o, 16));
        float e = expf(lg - mx);
        float se = e;
#pragma unroll
        for (int o = 8; o; o >>= 1) se += __shfl_xor(se, o, 16);
        attn[tid] = e / se;
    }
    __syncthreads();
    for (int c = tid; c < 640; c += 256) {
        float acc = 0.f;
        if (c < 512) {
            int h = c >> 6, t = c & 63;
#pragma unroll
            for (int m = 0; m < 16; ++m)
                acc = fmaf(attn[h * 16 + m], qkv[(size_t)jn[m] * 1536 + 1024 + h * 64 + t], acc);
        } else {
            int d = c - 512, h = d >> 4, t = d & 15;
#pragma unroll
            for (int m = 0; m < 16; ++m)
                acc = fmaf(attn[h * 16 + m], edge[((size_t)n * 16 + m) * 128 + h * 16 + t], acc);
        }
        scec[(size_t)n * 640 + c] = f2bf(acc);
    }
}

// ---------------------------------------------------------------------------
extern "C" void kernel_launch(void* const* d_in, const int* in_sizes, int n_in,
                              void* d_out, int out_size, void* d_ws, size_t ws_size,
                              hipStream_t stream) {
    const float* gene_exp = (const float*)d_in[0];
    const float* token_embs = (const float*)d_in[1];
    const float* coords = (const float*)d_in[2];
    const int* nbr = (const int*)d_in[3];
    const float* w_qkv = (const float*)d_in[4];
    const float* b_qkv = (const float*)d_in[5];
    const float* wa1 = (const float*)d_in[6];
    const float* ba1 = (const float*)d_in[7];
    const float* wa2 = (const float*)d_in[8];
    const float* ba2 = (const float*)d_in[9];
    const float* we1 = (const float*)d_in[10];
    const float* be1 = (const float*)d_in[11];
    const float* we2 = (const float*)d_in[12];
    const float* be2 = (const float*)d_in[13];
    const float* wo1 = (const float*)d_in[14];
    const float* bo1 = (const float*)d_in[15];
    const float* wo2 = (const float*)d_in[16];
    const float* bo2 = (const float*)d_in[17];
    const float* wm1 = (const float*)d_in[18];
    const float* bm1 = (const float*)d_in[19];
    const float* wm2 = (const float*)d_in[20];
    const float* bm2 = (const float*)d_in[21];
    const float* wg1 = (const float*)d_in[22];
    const float* bg1 = (const float*)d_in[23];
    const float* wg2 = (const float*)d_in[24];
    const float* bg2 = (const float*)d_in[25];

    float* out = (float*)d_out;
    float* gene_out = out;             // [2048, 50]
    float* tok_out = out + 2048 * 50;  // [2048, 512]

    float* ws = (float*)d_ws;
    size_t o = 0;
    auto alloc = [&](size_t nf) {
        float* p = ws + o;
        o += nf;
        return p;
    };
    typedef unsigned short us;
    us* x_ln_bf = (us*)alloc((size_t)2048 * 512 / 2);
    float* qkvb = alloc((size_t)2048 * 1536);
    us* q2b = (us*)alloc((size_t)16384 * 64 / 2);
    us* k2b = (us*)alloc((size_t)16384 * 64 / 2);
    us* qpb = (us*)alloc((size_t)16384 * 512 / 2);
    us* kpb = (us*)alloc((size_t)16384 * 512 / 2);
    float* gep = alloc((size_t)2048 * 512);
    float* edgeb = alloc((size_t)2048 * 16 * 128);
    float* logitsb = alloc((size_t)2048 * 128);
    us* scec_bf = (us*)alloc((size_t)2048 * 640 / 2);
    float* buf1 = alloc((size_t)2048 * 512);
    us* buf1_bf = (us*)alloc((size_t)2048 * 512 / 2);
    float* buf2 = alloc((size_t)2048 * 2048);
    us* buf2_bf = (us*)alloc((size_t)2048 * 2048 / 2);
    float* tok1 = alloc((size_t)2048 * 512);
    us* tok1_bf = (us*)alloc((size_t)2048 * 512 / 2);
    us* tokout_bf = (us*)alloc((size_t)2048 * 512 / 2);
    us* u_bf = (us*)alloc((size_t)32768 * 128 / 2);
    float* projs = alloc((size_t)32768 * 2);
    float* rns = alloc((size_t)32768);
    us* qkvT = (us*)alloc((size_t)1536 * 512 / 2);
    us* wa1qT = (us*)alloc((size_t)512 * 64 / 2);
    us* wa1kT = (us*)alloc((size_t)512 * 64 / 2);
    us* we2T = (us*)alloc((size_t)128 * 128 / 2);
    us* wo1T = (us*)alloc((size_t)512 * 640 / 2);
    us* wo2T = (us*)alloc((size_t)512 * 512 / 2);
    us* wm1T = (us*)alloc((size_t)2048 * 512 / 2);
    us* wm2T = (us*)alloc((size_t)512 * 2048 / 2);
    us* wg1T = (us*)alloc((size_t)512 * 512 / 2);
    if (o * sizeof(float) > ws_size) return;  // ~132 MB required

    auto T = [&](const float* W, us* Wt, int K, int N) {
        tcast_kernel<<<dim3((N + 31) / 32, (K + 31) / 32), 256, 0, stream>>>(W, Wt, K, N);
    };
    auto G = [&](const us* A, const us* Bt, const float* bias, const float* resid,
                 float* outF, us* outB, int M, int K, int N) {
        gemm_bf16_kernel<<<dim3(N / 128, M / 128), 256, 0, stream>>>(A, Bt, bias, resid,
                                                                     outF, outB, M, K, N);
    };

    // 0. weight transpose-casts (independent)
    T(w_qkv, qkvT, 512, 1536);
    T(wa1, wa1qT, 64, 512);
    T(wa1 + 64 * 512, wa1kT, 64, 512);
    T(we2, we2T, 128, 128);
    T(wo1, wo1T, 640, 512);
    T(wo2, wo2T, 512, 512);
    T(wm1, wm1T, 512, 2048);
    T(wm2, wm2T, 2048, 512);
    T(wg1, wg1T, 512, 512);

    // 1. x_ln_bf = LN(token_embs) (bf16)
    act_ln_kernel<<<2048, 256, 0, stream>>>(nullptr, x_ln_bf, token_embs, 512, 0);
    // 2. qkv = x_ln @ w_qkv + b_qkv (fp32 out; v used fp32 later)
    G(x_ln_bf, qkvT, b_qkv, nullptr, qkvb, nullptr, 2048, 512, 1536);
    // 3. repack q,k -> bf16 [16384,64]
    repack_qk<<<4096, 256, 0, stream>>>(qkvb, q2b, k2b);
    // 4-5. q/k fc1 pieces -> bf16 [16384,512]
    G(q2b, wa1qT, nullptr, nullptr, nullptr, qpb, 16384, 64, 512);
    G(k2b, wa1kT, nullptr, nullptr, nullptr, kpb, 16384, 64, 512);
    // 6. gene fc1 piece (K=50, fp32 kernel)
    gemm_kernel<<<dim3(8, 32), 256, 0, stream>>>(gene_exp, wa1 + 144 * 512, nullptr, nullptr,
                                                 gep, 2048, 50, 512);
    // 7. frame-averaged edge features
    proj_kernel<<<128, 256, 0, stream>>>(coords, nbr, projs, rns);
    frame_mlp1_kernel<<<8192, 256, 0, stream>>>(projs, rns, we1, be1, u_bf);
    G(u_bf, we2T, be2, nullptr, edgeb, nullptr, 32768, 128, 128);
    // 8. fused attention-MLP logits
    logits_kernel<<<2048, 256, 0, stream>>>(qpb, kpb, gep, edgeb, nbr, wa1, ba1, wa2, ba2,
                                            logitsb);
    // 9. softmax + context aggregation -> scec bf16
    smax_agg_kernel<<<2048, 256, 0, stream>>>(logitsb, qkvb, edgeb, nbr, scec_bf);
    // 10. ctx = mlp2(scec, wo1, wo2); tok1 = token_embs + ctx
    G(scec_bf, wo1T, bo1, nullptr, buf1, nullptr, 2048, 640, 512);
    act_ln_kernel<<<2048, 256, 0, stream>>>(nullptr, buf1_bf, buf1, 512, 1);
    G(buf1_bf, wo2T, bo2, token_embs, tok1, tok1_bf, 2048, 512, 512);
    // 11. tok2 = tok1 + mlp2(tok1, wm1, wm2) -> d_out tok section
    G(tok1_bf, wm1T, bm1, nullptr, buf2, nullptr, 2048, 512, 2048);
    act_ln_kernel<<<2048, 256, 0, stream>>>(nullptr, buf2_bf, buf2, 2048, 1);
    G(buf2_bf, wm2T, bm2, tok1, tok_out, tokout_bf, 2048, 2048, 512);
    // 12. gene_out = mlp2(tok2, wg1, wg2)
    G(tokout_bf, wg1T, bg1, nullptr, buf1, nullptr, 2048, 512, 512);
    act_ln_kernel<<<2048, 256, 0, stream>>>(buf1, nullptr, buf1, 512, 1);
    gemm_kernel<<<dim3(1, 32), 256, 0, stream>>>(buf1, wg2, bg2, nullptr, gene_out, 2048, 512, 50);
}